// Round 6
// baseline (55406.775 us; speedup 1.0000x reference)
//
#include <hip/hip_runtime.h>

// All tensors fp32. Conv = sum over taps of shifted GEMM, LDS-tiled.

struct Taps { int kw[7]; int joff[7]; };

// ---------------------------------------------------------------------------
// Weight transpose: w[O][I][K] -> wt[K][I][O] (writes coalesced)
// ---------------------------------------------------------------------------
__global__ __launch_bounds__(256) void tw_k(
    const float* __restrict__ w, float* __restrict__ wt,
    int Cout, int Cin, int K, int n)
{
    int idx = blockIdx.x * 256 + threadIdx.x;
    if (idx >= n) return;
    int o = idx % Cout;
    int r = idx / Cout;
    int i = r % Cin;
    int k = r / Cin;
    wt[idx] = w[((size_t)o * Cin + i) * K + k];
}

// ---------------------------------------------------------------------------
// Tiled conv: 64 Cout x 64 t' per block, 256 threads, 4x4 micro-tile.
// out[b, o, t'*OS+OR] = bias[o] + sum_tau sum_i W[o,i,kw(tau)] * in[b,i,t'*JS+joff(tau)]
// Optional fused input GN+ReLU (scale/shift per (b,cin)), residual, out relu,
// z-transposed store ([b*L + t]*Cout + o).
// ---------------------------------------------------------------------------
template<int KP, int JWMAX>
__global__ __launch_bounds__(256) void convt_tiled_k(
    const float* __restrict__ in, const float* __restrict__ wt,
    const float* __restrict__ bias, float* __restrict__ outp,
    const float* __restrict__ scale, const float* __restrict__ shift,
    const float* __restrict__ resid,
    int Cin, int Lin, int LoutT, int Cout,
    int minoff, int JW, int JS, int OS, int OR,
    int relu, int zstore, Taps taps)
{
    __shared__ float bs[32][JWMAX];
    __shared__ float ws[32][64];
    const int tid = threadIdx.x;
    const int tx = tid & 15, ty = tid >> 4;
    const int t0 = blockIdx.x * 64, o0 = blockIdx.y * 64, b = blockIdx.z;

    float acc[4][4];
    #pragma unroll
    for (int cc = 0; cc < 4; ++cc)
        #pragma unroll
        for (int tt = 0; tt < 4; ++tt) acc[cc][tt] = 0.f;

    const int JB = t0 * JS + minoff;
    const float* inb = in + (size_t)b * Cin * Lin;
    const int nstage = 32 * JW;

    for (int ic = 0; ic < Cin; ic += 32) {
        __syncthreads();
        for (int f = tid; f < nstage; f += 256) {
            int r = f / JW, c = f - r * JW;
            int j = JB + c;
            float v = 0.f;
            if (j >= 0 && j < Lin) {
                v = inb[(size_t)(ic + r) * Lin + j];
                if (scale) {
                    int ci = b * Cin + ic + r;
                    v = fmaxf(v * scale[ci] + shift[ci], 0.f);
                }
            }
            bs[r][c] = v;
        }
        #pragma unroll
        for (int tau = 0; tau < KP; ++tau) {
            if (tau > 0) __syncthreads();
            const float* wtk = wt + ((size_t)taps.kw[tau] * Cin + ic) * Cout + o0;
            for (int f = tid; f < 2048; f += 256) {
                int i = f >> 6, o = f & 63;
                ws[i][o] = wtk[(size_t)i * Cout + o];
            }
            __syncthreads();
            const int offc = taps.joff[tau] - minoff;
            const int cb0 = tx * 4 * JS + offc;
            const int cb1 = cb0 + JS, cb2 = cb0 + 2 * JS, cb3 = cb0 + 3 * JS;
            for (int i = 0; i < 32; ++i) {
                float4 a = *(const float4*)&ws[i][ty * 4];
                float b0 = bs[i][cb0];
                float b1 = bs[i][cb1];
                float b2 = bs[i][cb2];
                float b3 = bs[i][cb3];
                acc[0][0] += a.x * b0; acc[0][1] += a.x * b1; acc[0][2] += a.x * b2; acc[0][3] += a.x * b3;
                acc[1][0] += a.y * b0; acc[1][1] += a.y * b1; acc[1][2] += a.y * b2; acc[1][3] += a.y * b3;
                acc[2][0] += a.z * b0; acc[2][1] += a.z * b1; acc[2][2] += a.z * b2; acc[2][3] += a.z * b3;
                acc[3][0] += a.w * b0; acc[3][1] += a.w * b1; acc[3][2] += a.w * b2; acc[3][3] += a.w * b3;
            }
        }
    }

    const int Lfull = LoutT * OS;
    #pragma unroll
    for (int cc = 0; cc < 4; ++cc) {
        int o = o0 + ty * 4 + cc;
        float bv = bias ? bias[o] : 0.f;
        #pragma unroll
        for (int tt = 0; tt < 4; ++tt) {
            int tg = (t0 + tx * 4 + tt) * OS + OR;
            float v = acc[cc][tt] + bv;
            size_t oi;
            if (zstore) oi = ((size_t)b * Lfull + tg) * Cout + o;
            else        oi = ((size_t)b * Cout + o) * Lfull + tg;
            if (resid) v += resid[oi];
            if (relu) v = fmaxf(v, 0.f);
            outp[oi] = v;
        }
    }
}

// ---------------------------------------------------------------------------
// GroupNorm stats -> per-(b,c) scale/shift (eps 1e-5)
// ---------------------------------------------------------------------------
__global__ __launch_bounds__(256) void gnstats_k(
    const float* __restrict__ x, const float* __restrict__ g,
    const float* __restrict__ be, float* __restrict__ scale,
    float* __restrict__ shift, int C, int L, int G)
{
    int tid = threadIdx.x;
    int b = blockIdx.x / G, gr = blockIdx.x % G;
    int cpg = C / G;
    size_t n = (size_t)cpg * L;
    const float* base = x + ((size_t)b * C + (size_t)gr * cpg) * L;
    float s = 0.f, s2 = 0.f;
    for (size_t idx = tid; idx < n; idx += 256) { float v = base[idx]; s += v; s2 += v * v; }
    __shared__ float rs[256], rq[256];
    rs[tid] = s; rq[tid] = s2; __syncthreads();
    for (int off = 128; off > 0; off >>= 1) {
        if (tid < off) { rs[tid] += rs[tid + off]; rq[tid] += rq[tid + off]; }
        __syncthreads();
    }
    float mean = rs[0] / (float)n;
    float var  = rq[0] / (float)n - mean * mean;
    float inv  = rsqrtf(var + 1e-5f);
    if (tid < cpg) {
        int c = gr * cpg + tid;
        float ga = g[c], bb = be[c];
        scale[b * C + c] = inv * ga;
        shift[b * C + c] = bb - mean * inv * ga;
    }
}

// ---------------------------------------------------------------------------
// VQ: 64 positions/block, 16 code-tiles of 64, 4x4 register dot tiles.
// ---------------------------------------------------------------------------
__global__ __launch_bounds__(256) void vq_k(
    const float* __restrict__ z,       // [32768,128]
    const float* __restrict__ cb,      // [1024,128]
    float* __restrict__ out_q,         // [B,128,1024]
    float* __restrict__ lossAcc,
    unsigned int* __restrict__ hist,
    int* __restrict__ ip_out)
{
    const int tid = threadIdx.x;
    const int pbase = blockIdx.x * 64;
    __shared__ float zs[64 * 129];
    __shared__ float cbs[64 * 129];
    __shared__ float cn[64];
    __shared__ float rd[256];
    __shared__ int   ri[256];
    __shared__ int   ip[64];

    for (int f = tid; f < 64 * 128; f += 256) {
        int p = f >> 7, d = f & 127;
        zs[p * 129 + d] = z[(size_t)pbase * 128 + f];
    }

    float mind[4]; int minc[4];
    #pragma unroll
    for (int a = 0; a < 4; ++a) { mind[a] = 3.4e38f; minc[a] = 0; }
    const int tp = tid >> 4, tr = tid & 15;
    const int prow = tp * 4, crow = tr * 4;

    for (int ct = 0; ct < 16; ++ct) {
        __syncthreads();
        for (int f = tid; f < 64 * 128; f += 256) {
            int c = f >> 7, d = f & 127;
            cbs[c * 129 + d] = cb[((size_t)ct * 64 + c) * 128 + d];
        }
        __syncthreads();
        if (tid < 64) {
            float s = 0.f;
            for (int d = 0; d < 128; ++d) { float v = cbs[tid * 129 + d]; s += v * v; }
            cn[tid] = s;
        }
        __syncthreads();
        float dot[4][4];
        #pragma unroll
        for (int a = 0; a < 4; ++a)
            #pragma unroll
            for (int e = 0; e < 4; ++e) dot[a][e] = 0.f;
        for (int d = 0; d < 128; ++d) {
            float za[4], cc[4];
            #pragma unroll
            for (int a = 0; a < 4; ++a) za[a] = zs[(prow + a) * 129 + d];
            #pragma unroll
            for (int e = 0; e < 4; ++e) cc[e] = cbs[(crow + e) * 129 + d];
            #pragma unroll
            for (int a = 0; a < 4; ++a)
                #pragma unroll
                for (int e = 0; e < 4; ++e) dot[a][e] += za[a] * cc[e];
        }
        #pragma unroll
        for (int e = 0; e < 4; ++e) {
            int c = ct * 64 + crow + e;
            float cne = cn[crow + e];
            #pragma unroll
            for (int a = 0; a < 4; ++a) {
                float dist = cne - 2.0f * dot[a][e];
                if (dist < mind[a]) { mind[a] = dist; minc[a] = c; }
            }
        }
    }

    for (int a = 0; a < 4; ++a) {
        __syncthreads();
        rd[tid] = mind[a]; ri[tid] = minc[a];
        __syncthreads();
        if (tr == 0) {
            float bd = rd[tid]; int bi = ri[tid];
            for (int u = 1; u < 16; ++u) {
                float dv = rd[tid + u]; int iv = ri[tid + u];
                if (dv < bd || (dv == bd && iv < bi)) { bd = dv; bi = iv; }
            }
            ip[prow + a] = bi;
            atomicAdd(&hist[bi], 1u);
        }
    }
    __syncthreads();

    if (tid < 64) ip_out[pbase + tid] = ip[tid];

    float lp = 0.f;
    for (int f = tid; f < 64 * 128; f += 256) {
        int p = f >> 7, d = f & 127;
        int gp = pbase + p, b = gp >> 10, l = gp & 1023;
        float qv = cb[(size_t)ip[p] * 128 + d];
        float zv = zs[p * 129 + d];
        float df = qv - zv; lp += df * df;
        out_q[(((size_t)b * 128 + d) << 10) + l] = qv;
    }
    rd[tid] = lp; __syncthreads();
    for (int off = 128; off > 0; off >>= 1) {
        if (tid < off) rd[tid] += rd[tid + off];
        __syncthreads();
    }
    if (tid == 0) atomicAdd(lossAcc, rd[0]);
}

__global__ __launch_bounds__(256) void enc_k(
    const int* __restrict__ ip, float2* __restrict__ enc)
{
    size_t idx = (size_t)blockIdx.x * 256 + threadIdx.x;   // 16,777,216 float2
    int p  = (int)(idx >> 9);
    int q2 = (int)(idx & 511);
    int best = ip[p];
    int c0 = q2 * 2;
    float2 v;
    v.x = (c0     == best) ? 1.0f : 0.0f;
    v.y = (c0 + 1 == best) ? 1.0f : 0.0f;
    enc[idx] = v;
}

__global__ __launch_bounds__(256) void pool_k(const float* __restrict__ q, float* __restrict__ zp)
{
    int tid = threadIdx.x;
    const float* row = q + (size_t)blockIdx.x * 1024;
    float s = 0.f;
    for (int l = tid; l < 1024; l += 256) s += row[l];
    __shared__ float rs[256];
    rs[tid] = s; __syncthreads();
    for (int off = 128; off > 0; off >>= 1) {
        if (tid < off) rs[tid] += rs[tid + off];
        __syncthreads();
    }
    if (tid == 0) zp[blockIdx.x] = rs[0] * (1.0f / 1024.0f);
}

__global__ __launch_bounds__(256) void beh_k(
    const float* __restrict__ zp,
    const float* __restrict__ w1, const float* __restrict__ b1,
    const float* __restrict__ w2, const float* __restrict__ b2,
    const float* __restrict__ w3, const float* __restrict__ b3,
    float* __restrict__ out)
{
    __shared__ float zs[32 * 128];
    __shared__ float h1s[32 * 128];
    __shared__ float h2s[32 * 64];
    int tid = threadIdx.x;
    for (int f = tid; f < 4096; f += 256) zs[f] = zp[f];
    __syncthreads();
    for (int f = tid; f < 4096; f += 256) {
        int bi = f >> 7, j = f & 127;
        float acc = b1[j];
        for (int d = 0; d < 128; ++d) acc += zs[bi * 128 + d] * w1[j * 128 + d];
        h1s[f] = fmaxf(acc, 0.f);
    }
    __syncthreads();
    for (int f = tid; f < 2048; f += 256) {
        int bi = f >> 6, j = f & 63;
        float acc = b2[j];
        for (int d = 0; d < 128; ++d) acc += h1s[bi * 128 + d] * w2[j * 128 + d];
        h2s[f] = fmaxf(acc, 0.f);
    }
    __syncthreads();
    if (tid < 128) {
        int bi = tid >> 2, j = tid & 3;
        float acc = b3[j];
        for (int d = 0; d < 64; ++d) acc += h2s[bi * 64 + d] * w3[j * 64 + d];
        out[tid] = acc;
    }
}

__global__ __launch_bounds__(1024) void init_k(unsigned int* hist, float* lossAcc)
{
    hist[threadIdx.x] = 0u;
    if (threadIdx.x == 0) *lossAcc = 0.f;
}

__global__ __launch_bounds__(1024) void fin_k(
    const unsigned int* __restrict__ hist, const float* __restrict__ lossAcc,
    float* __restrict__ out_loss, float* __restrict__ out_perp)
{
    __shared__ float rs[1024];
    int tid = threadIdx.x;
    float avg = (float)hist[tid] * (1.0f / 32768.0f);
    rs[tid] = avg * logf(avg + 1e-10f);
    __syncthreads();
    for (int off = 512; off > 0; off >>= 1) {
        if (tid < off) rs[tid] += rs[tid + off];
        __syncthreads();
    }
    if (tid == 0) {
        out_perp[0] = expf(-rs[0]);
        out_loss[0] = 0.25f * lossAcc[0] * (1.0f / 4194304.0f);
    }
}

// ---------------------------------------------------------------------------
static inline Taps mkTapsConv(int K, int pad) {
    Taps t{};
    for (int k = 0; k < 7; ++k) { t.kw[k] = (k < K) ? k : 0; t.joff[k] = (k < K) ? (k - pad) : 0; }
    return t;
}

extern "C" void kernel_launch(void* const* d_in, const int* in_sizes, int n_in,
                              void* d_out, int out_size, void* d_ws, size_t ws_size,
                              hipStream_t stream)
{
    const float* X    = (const float*)d_in[0];
    const float* e1w  = (const float*)d_in[1];  const float* e1b = (const float*)d_in[2];
    const float* e2w  = (const float*)d_in[3];  const float* e2b = (const float*)d_in[4];
    const float* e3w  = (const float*)d_in[5];  const float* e3b = (const float*)d_in[6];
    const float* r0g1g = (const float*)d_in[7];  const float* r0g1b = (const float*)d_in[8];
    const float* r0c1w = (const float*)d_in[9];
    const float* r0g2g = (const float*)d_in[10]; const float* r0g2b = (const float*)d_in[11];
    const float* r0c2w = (const float*)d_in[12];
    const float* r1g1g = (const float*)d_in[13]; const float* r1g1b = (const float*)d_in[14];
    const float* r1c1w = (const float*)d_in[15];
    const float* r1g2g = (const float*)d_in[16]; const float* r1g2b = (const float*)d_in[17];
    const float* r1c2w = (const float*)d_in[18];
    const float* pvw  = (const float*)d_in[19]; const float* pvb = (const float*)d_in[20];
    const float* CB   = (const float*)d_in[21];
    const float* d1w  = (const float*)d_in[22]; const float* d1b = (const float*)d_in[23];
    const float* d2w  = (const float*)d_in[24]; const float* d2b = (const float*)d_in[25];
    const float* d3w  = (const float*)d_in[26]; const float* d3b = (const float*)d_in[27];
    const float* bh1w = (const float*)d_in[28]; const float* bh1b = (const float*)d_in[29];
    const float* bh2w = (const float*)d_in[30]; const float* bh2b = (const float*)d_in[31];
    const float* bh3w = (const float*)d_in[32]; const float* bh3b = (const float*)d_in[33];

    // ---- output regions (fp32 elements) ----
    float* out = (float*)d_out;
    const size_t N_XREC = 16777216ull, N_Q = 4194304ull, N_ENC = 33554432ull;
    float* out_loss = out;
    float* out_xrec = out + 1;
    float* out_perp = out + 1 + N_XREC;
    float* out_q    = out + 2 + N_XREC;
    float* out_enc  = out + 2 + N_XREC + N_Q;
    float* out_beh  = out + 2 + N_XREC + N_Q + N_ENC;

    // ---- d_out scratch staging ----
    // xrec region (16,777,216 floats):
    float* h1q  = out_xrec;                 // [8,128,4096] per-quarter
    float* t2f  = out_xrec;                 // [32,128,1024] full (after encoder)
    float* scA  = out_xrec + 15000000;      // 16,384 (32x512)
    float* shA  = scA + 16384;
    float* scB  = shA + 16384;              //  4,096 (32x128)
    float* shB  = scB + 4096;
    // enc region (33,554,432 floats):
    float* z    = out_enc;                  // [32768,128]
    float* h2q  = out_enc + 4194304;        // [8,256,2048] per-quarter
    float* h3f  = out_enc + 8388608;        // [32,512,1024] full
    float* d1o  = out_enc + 8388608;        // [8,512,2048] per-quarter (decoder)
    float* d2o  = out_enc + 16777216;       // [8,256,4096] per-quarter
    float* wtb  = out_enc + 25165824;       // transposed weights (~2.35M floats)

    float* wtE1 = wtb;                 // 114,688
    float* wtE2 = wtb + 114688;        // 163,840
    float* wtE3 = wtb + 278528;        // 393,216
    float* wtC1r0 = wtb + 671744;      // 196,608
    float* wtC2r0 = wtb + 868352;      // 65,536
    float* wtC1r1 = wtb + 933888;      // 196,608
    float* wtC2r1 = wtb + 1130496;     // 65,536
    float* wtPV  = wtb + 1196032;      // 65,536
    float* wtD1  = wtb + 1261568;      // 196,608
    float* wtD2  = wtb + 1458176;      // 655,360
    float* wtD3  = wtb + 2113536;      // 229,376

    // ---- d_ws: smalls only (~155 KB) ----
    float* W = (float*)d_ws;
    float* lossA = W;
    unsigned int* hist = (unsigned int*)(W + 16);
    float* zp   = W + 16 + 1024;
    int* ipArr  = (int*)(W + 16 + 1024 + 4096);

    init_k<<<dim3(1), dim3(1024), 0, stream>>>(hist, lossA);

    // ---- weight transposes ----
    auto tw = [&](const float* w, float* wt, int Co, int Ci, int K) {
        int n = Co * Ci * K;
        tw_k<<<dim3((n + 255) / 256), 256, 0, stream>>>(w, wt, Co, Ci, K, n);
    };
    tw(e1w, wtE1, 128, 128, 7);
    tw(e2w, wtE2, 256, 128, 5);
    tw(e3w, wtE3, 512, 256, 3);
    tw(r0c1w, wtC1r0, 128, 512, 3);
    tw(r0c2w, wtC2r0, 512, 128, 1);
    tw(r1c1w, wtC1r1, 128, 512, 3);
    tw(r1c2w, wtC2r1, 512, 128, 1);
    tw(pvw, wtPV, 128, 512, 1);
    tw(d1w, wtD1, 512, 128, 3);
    tw(d2w, wtD2, 256, 512, 5);
    tw(d3w, wtD3, 128, 256, 7);

    // ---- encoder e1..e3 per batch-quarter; h3 accumulates full-batch ----
    for (int q = 0; q < 4; ++q) {
        const float* Xq = X + (size_t)q * 8 * 128 * 4096;
        convt_tiled_k<7, 72><<<dim3(64, 2, 8), 256, 0, stream>>>(
            Xq, wtE1, e1b, h1q, nullptr, nullptr, nullptr,
            128, 4096, 4096, 128, -3, 70, 1, 1, 0, 1, 0, mkTapsConv(7, 3));
        convt_tiled_k<5, 132><<<dim3(32, 4, 8), 256, 0, stream>>>(
            h1q, wtE2, e2b, h2q, nullptr, nullptr, nullptr,
            128, 4096, 2048, 256, -2, 131, 2, 1, 0, 1, 0, mkTapsConv(5, 2));
        convt_tiled_k<3, 132><<<dim3(16, 8, 8), 256, 0, stream>>>(
            h2q, wtE3, e3b, h3f + (size_t)q * 4194304, nullptr, nullptr, nullptr,
            256, 2048, 1024, 512, -1, 129, 2, 1, 0, 0, 0, mkTapsConv(3, 1));
    }

    // ---- res blocks, full batch ----
    const float* c1w[2] = { wtC1r0, wtC1r1 };
    const float* c2w[2] = { wtC2r0, wtC2r1 };
    const float* g1g[2] = { r0g1g, r1g1g }; const float* g1b[2] = { r0g1b, r1g1b };
    const float* g2g[2] = { r0g2g, r1g2g }; const float* g2b[2] = { r0g2b, r1g2b };
    for (int r = 0; r < 2; ++r) {
        gnstats_k<<<dim3(256), 256, 0, stream>>>(h3f, g1g[r], g1b[r], scA, shA, 512, 1024, 8);
        convt_tiled_k<3, 72><<<dim3(16, 2, 32), 256, 0, stream>>>(
            h3f, c1w[r], nullptr, t2f, scA, shA, nullptr,
            512, 1024, 1024, 128, -1, 66, 1, 1, 0, 0, 0, mkTapsConv(3, 1));
        gnstats_k<<<dim3(256), 256, 0, stream>>>(t2f, g2g[r], g2b[r], scB, shB, 128, 1024, 8);
        convt_tiled_k<1, 72><<<dim3(16, 8, 32), 256, 0, stream>>>(
            t2f, c2w[r], nullptr, h3f, scB, shB, h3f,
            128, 1024, 1024, 512, 0, 64, 1, 1, 0, 0, 0, mkTapsConv(1, 0));
    }

    // ---- pre-VQ 1x1 conv, transposed z store, full batch ----
    convt_tiled_k<1, 72><<<dim3(16, 2, 32), 256, 0, stream>>>(
        h3f, wtPV, pvb, z, nullptr, nullptr, nullptr,
        512, 1024, 1024, 128, 0, 64, 1, 1, 0, 0, 1, mkTapsConv(1, 0));

    // ---- VQ ----
    vq_k<<<dim3(512), 256, 0, stream>>>(z, CB, out_q, lossA, hist, ipArr);

    // ---- behavior head ----
    pool_k<<<dim3(4096), 256, 0, stream>>>(out_q, zp);
    beh_k<<<dim3(1), 256, 0, stream>>>(zp, bh1w, bh1b, bh2w, bh2b, bh3w, bh3b, out_beh);

    // ---- decoder per batch-quarter (parity-split transposed convs) ----
    Taps d1e{}; d1e.kw[0] = 1; d1e.joff[0] = 0;
    Taps d1od{}; d1od.kw[0] = 0; d1od.joff[0] = 0; d1od.kw[1] = 2; d1od.joff[1] = 1;
    Taps d2e{}; d2e.kw[0] = 0; d2e.joff[0] = -1; d2e.kw[1] = 2; d2e.joff[1] = 0; d2e.kw[2] = 4; d2e.joff[2] = 1;
    Taps d2od{}; d2od.kw[0] = 1; d2od.joff[0] = 0; d2od.kw[1] = 3; d2od.joff[1] = 1;
    for (int q = 0; q < 4; ++q) {
        const float* qin = out_q + (size_t)q * 1048576;
        convt_tiled_k<1, 72><<<dim3(16, 8, 8), 256, 0, stream>>>(
            qin, wtD1, d1b, d1o, nullptr, nullptr, nullptr,
            128, 1024, 1024, 512, 0, 64, 1, 2, 0, 1, 0, d1e);
        convt_tiled_k<2, 72><<<dim3(16, 8, 8), 256, 0, stream>>>(
            qin, wtD1, d1b, d1o, nullptr, nullptr, nullptr,
            128, 1024, 1024, 512, 0, 65, 1, 2, 1, 1, 0, d1od);
        convt_tiled_k<3, 72><<<dim3(32, 4, 8), 256, 0, stream>>>(
            d1o, wtD2, d2b, d2o, nullptr, nullptr, nullptr,
            512, 2048, 2048, 256, -1, 66, 1, 2, 0, 1, 0, d2e);
        convt_tiled_k<2, 72><<<dim3(32, 4, 8), 256, 0, stream>>>(
            d1o, wtD2, d2b, d2o, nullptr, nullptr, nullptr,
            512, 2048, 2048, 256, 0, 65, 1, 2, 1, 1, 0, d2od);
        convt_tiled_k<7, 72><<<dim3(64, 2, 8), 256, 0, stream>>>(
            d2o, wtD3, d3b, out_xrec + (size_t)q * 4194304, nullptr, nullptr, nullptr,
            256, 4096, 4096, 128, -3, 70, 1, 1, 0, 0, 0, mkTapsConv(7, 3));
    }

    // ---- one-hot enc (overwrites enc-region scratch) ----
    enc_k<<<dim3(65536), 256, 0, stream>>>(ipArr, (float2*)out_enc);

    // ---- loss + perplexity ----
    fin_k<<<dim3(1), 1024, 0, stream>>>(hist, lossA, out_loss, out_perp);
}